// Round 4
// baseline (897.492 us; speedup 1.0000x reference)
//
#include <hip/hip_runtime.h>
#include <math.h>

// Problem constants (match reference)
constexpr int NN = 100000;     // nodes
constexpr int DF = 512;        // input features
constexpr int C1 = 32;         // layer-1 width
constexpr int C2 = 16;         // layer-2 width
constexpr long long NE = 3200000;
#define EPS_NORM 1e-7f

// ---------------------------------------------------------------------------
// gemm1: XW1[row][0..31] = X[row][:] @ W1   (one thread per row)
// W1 index is wave-uniform -> compiler emits scalar s_load broadcasts.
// X row read as sequential float4 stream per lane.
// ---------------------------------------------------------------------------
__global__ __launch_bounds__(256) void gemm1_k(const float* __restrict__ X,
                                               const float* __restrict__ W1,
                                               float* __restrict__ XW1) {
    int row = blockIdx.x * 256 + threadIdx.x;
    if (row >= NN) return;
    float acc[C1];
#pragma unroll
    for (int j = 0; j < C1; ++j) acc[j] = 0.f;
    const float4* xr = reinterpret_cast<const float4*>(X + (size_t)row * DF);
#pragma unroll 2
    for (int k4 = 0; k4 < DF / 4; ++k4) {
        float4 xv = xr[k4];
        const float* w = W1 + k4 * 4 * C1;   // uniform address
#pragma unroll
        for (int j = 0; j < C1; ++j) acc[j] = fmaf(xv.x, w[j], acc[j]);
#pragma unroll
        for (int j = 0; j < C1; ++j) acc[j] = fmaf(xv.y, w[C1 + j], acc[j]);
#pragma unroll
        for (int j = 0; j < C1; ++j) acc[j] = fmaf(xv.z, w[2 * C1 + j], acc[j]);
#pragma unroll
        for (int j = 0; j < C1; ++j) acc[j] = fmaf(xv.w, w[3 * C1 + j], acc[j]);
    }
    float4* o = reinterpret_cast<float4*>(XW1 + (size_t)row * C1);
#pragma unroll
    for (int q = 0; q < C1 / 4; ++q)
        o[q] = make_float4(acc[4 * q], acc[4 * q + 1], acc[4 * q + 2], acc[4 * q + 3]);
}

// ---------------------------------------------------------------------------
// gemm2: HW2[row][0..15] = relu(H1[row][:]) @ W2   (one thread per row)
// ---------------------------------------------------------------------------
__global__ __launch_bounds__(256) void gemm2_k(const float* __restrict__ H1,
                                               const float* __restrict__ W2,
                                               float* __restrict__ HW2) {
    int row = blockIdx.x * 256 + threadIdx.x;
    if (row >= NN) return;
    float h[C1];
    const float4* hr = reinterpret_cast<const float4*>(H1 + (size_t)row * C1);
#pragma unroll
    for (int q = 0; q < C1 / 4; ++q) {
        float4 v = hr[q];
        h[4 * q + 0] = fmaxf(v.x, 0.f);
        h[4 * q + 1] = fmaxf(v.y, 0.f);
        h[4 * q + 2] = fmaxf(v.z, 0.f);
        h[4 * q + 3] = fmaxf(v.w, 0.f);
    }
    float acc[C2];
#pragma unroll
    for (int j = 0; j < C2; ++j) acc[j] = 0.f;
#pragma unroll
    for (int k = 0; k < C1; ++k) {
        const float* w = W2 + k * C2;   // uniform address
#pragma unroll
        for (int j = 0; j < C2; ++j) acc[j] = fmaf(h[k], w[j], acc[j]);
    }
    float4* o = reinterpret_cast<float4*>(HW2 + (size_t)row * C2);
#pragma unroll
    for (int q = 0; q < C2 / 4; ++q)
        o[q] = make_float4(acc[4 * q], acc[4 * q + 1], acc[4 * q + 2], acc[4 * q + 3]);
}

// ---------------------------------------------------------------------------
// spmm scatter: Hout[r][j] += val * Hin[c][j] over all edges.
// One work-item per (edge, feature); grid-stride. F is a power of two.
// ---------------------------------------------------------------------------
template <int F>
__global__ __launch_bounds__(256) void spmm_k(const int* __restrict__ rows,
                                              const int* __restrict__ cols,
                                              const float* __restrict__ vals,
                                              const float* __restrict__ Hin,
                                              float* __restrict__ Hout) {
    constexpr int SH = (F == 32) ? 5 : 4;
    constexpr int MSK = F - 1;
    long long total = NE << SH;
    long long stride = (long long)gridDim.x * 256;
    for (long long idx = (long long)blockIdx.x * 256 + threadIdx.x; idx < total;
         idx += stride) {
        int e = (int)(idx >> SH);
        int j = (int)(idx & MSK);
        int r = rows[e];
        int c = cols[e];
        float v = vals[e];
        float contrib = v * Hin[(size_t)c * F + j];
        unsafeAtomicAdd(&Hout[(size_t)r * F + j], contrib);
    }
}

// ---------------------------------------------------------------------------
// normalize rows of H (N x 16) in place: H[r] /= max(||H[r]||_2, eps)
// 16 lanes per row, fully coalesced; shuffle reduce within 16-lane groups.
// ---------------------------------------------------------------------------
__global__ __launch_bounds__(256) void norm_k(float* __restrict__ H) {
    int t = blockIdx.x * 256 + threadIdx.x;
    if (t >= NN * C2) return;
    float v = H[t];
    float s = v * v;
#pragma unroll
    for (int m = 1; m < C2; m <<= 1) s += __shfl_xor(s, m, C2);
    float norm = sqrtf(s);
    H[t] = v / fmaxf(norm, EPS_NORM);
}

extern "C" void kernel_launch(void* const* d_in, const int* in_sizes, int n_in,
                              void* d_out, int out_size, void* d_ws, size_t ws_size,
                              hipStream_t stream) {
    const float* X = (const float*)d_in[0];
    const float* W1 = (const float*)d_in[1];
    const float* W2 = (const float*)d_in[2];
    const int* lap_rows = (const int*)d_in[3];
    const int* lap_cols = (const int*)d_in[4];
    const float* vals = (const float*)d_in[5];
    float* out = (float*)d_out;

    float* XW1 = (float*)d_ws;                      // NN*32 floats = 12.8 MB
    float* H1 = XW1 + (size_t)NN * C1;              // NN*32 floats = 12.8 MB
    float* HW2 = H1 + (size_t)NN * C1;              // NN*16 floats = 6.4 MB

    // zero the atomic accumulators (ws/out are poisoned 0xAA each call)
    hipMemsetAsync(H1, 0, (size_t)NN * C1 * sizeof(float), stream);
    hipMemsetAsync(out, 0, (size_t)NN * C2 * sizeof(float), stream);

    int rowBlocks = (NN + 255) / 256;
    gemm1_k<<<rowBlocks, 256, 0, stream>>>(X, W1, XW1);
    spmm_k<C1><<<16384, 256, 0, stream>>>(lap_rows, lap_cols, vals, XW1, H1);
    gemm2_k<<<rowBlocks, 256, 0, stream>>>(H1, W2, HW2);
    spmm_k<C2><<<8192, 256, 0, stream>>>(lap_rows, lap_cols, vals, HW2, out);
    norm_k<<<((NN * C2) + 255) / 256, 256, 0, stream>>>(out);
}